// Round 7
// baseline (275.347 us; speedup 1.0000x reference)
//
#include <hip/hip_runtime.h>

#define N_NODES 100000
#define N_EDGES 3200000
#define N_GRAPHS 64
constexpr int NC    = 196;                 // coarse buckets of 512 nodes (196*512=100352)
constexpr int PBLK  = 256;                 // partition blocks
constexpr int CHUNK = N_EDGES / PBLK;      // 12500 edges/block (exact)
constexpr int NBLK  = (N_NODES + 255) / 256;
constexpr int LBLK  = N_NODES / 32;        // 3125 exact: 32 nodes/block, 8 lanes/node

// ---- workspace layout (bytes), ~80MB total ----
constexpr size_t OFF_CNTG   = 0x0;         // int[64]
constexpr size_t OFF_BNS1   = 0x400;       // float[16]
constexpr size_t OFF_BNS2   = 0x500;       // float[32]
constexpr size_t OFF_BNS3   = 0x700;       // float[64]
constexpr size_t OFF_POOLED = 0x1000;      // float[64*32] = 8KB
constexpr size_t ZERO_BYTES = 0x3000;      // memset [0, here)
constexpr size_t OFF_SCSH1  = 0x3000;      // float[16]
constexpr size_t OFF_SCSH2  = 0x3400;      // float[32]
constexpr size_t OFF_SCSH3  = 0x3800;      // float[64]
constexpr size_t OFF_CBASE  = 0x4000;      // int[NC+1]
constexpr size_t OFF_BTOT   = 0x5000;      // int[NC]
constexpr size_t OFF_ROWPTR = 0x10000;     // int[N_NODES+1]
constexpr size_t OFF_HISTM  = 0x80000;     // int[NC*PBLK] ~200KB
constexpr size_t OFF_ES     = 0x200000;    // uint2[N_EDGES] 25.6MB (staging)
constexpr size_t OFF_EP     = 0x1B00000;   // uint2[N_EDGES] 25.6MB (CSR)
constexpr size_t OFF_T1     = 0x3400000;   // float[N_NODES*8]
constexpr size_t OFF_T2     = 0x3800000;   // float[N_NODES*16]
constexpr size_t OFF_T3     = 0x4000000;   // float[N_NODES*32]

// batch is sorted -> per-graph count via binary search (no atomics)
__global__ void cnt_kernel(const int* __restrict__ batch, int* __restrict__ cntg) {
    int g = threadIdx.x;
    if (g >= N_GRAPHS) return;
    int lo0 = 0, hi0 = N_NODES;
    while (lo0 < hi0) { int m = (lo0 + hi0) >> 1; if (batch[m] < g) lo0 = m + 1; else hi0 = m; }
    int lo1 = lo0, hi1 = N_NODES;
    while (lo1 < hi1) { int m = (lo1 + hi1) >> 1; if (batch[m] < g + 1) lo1 = m + 1; else hi1 = m; }
    cntg[g] = lo1 - lo0;
}

// per-block LDS coarse-bucket histogram (no global atomics)
__global__ __launch_bounds__(256) void k_hist(const int* __restrict__ dst,
                                              int* __restrict__ histM) {
    __shared__ int h[NC];
    for (int i = threadIdx.x; i < NC; i += 256) h[i] = 0;
    __syncthreads();
    int base = blockIdx.x * CHUNK;
    for (int i = threadIdx.x; i < CHUNK; i += 256)
        atomicAdd(&h[dst[base + i] >> 9], 1);
    __syncthreads();
    for (int i = threadIdx.x; i < NC; i += 256)
        histM[i * PBLK + blockIdx.x] = h[i];
}

// per-bucket exclusive scan over blocks; emit bucket totals
__global__ __launch_bounds__(256) void k_scan1(int* __restrict__ histM,
                                               int* __restrict__ btot) {
    __shared__ int sd[256];
    int b = blockIdx.x, t = threadIdx.x;
    int v = histM[b * PBLK + t];
    sd[t] = v;
    __syncthreads();
    for (int off = 1; off < 256; off <<= 1) {
        int x = (t >= off) ? sd[t - off] : 0;
        __syncthreads();
        sd[t] += x;
        __syncthreads();
    }
    histM[b * PBLK + t] = sd[t] - v;   // exclusive within bucket
    if (t == 255) btot[b] = sd[255];
}

// exclusive scan over bucket totals -> coarse bucket bases
__global__ __launch_bounds__(256) void k_scan2(const int* __restrict__ btot,
                                               int* __restrict__ cbase) {
    __shared__ int sd[256];
    int t = threadIdx.x;
    int v = (t < NC) ? btot[t] : 0;
    sd[t] = v;
    __syncthreads();
    for (int off = 1; off < 256; off <<= 1) {
        int x = (t >= off) ? sd[t - off] : 0;
        __syncthreads();
        sd[t] += x;
        __syncthreads();
    }
    if (t < NC) cbase[t] = sd[t] - v;
    if (t == 0) cbase[NC] = N_EDGES;
}

// partition edges into coarse-bucket sub-streams; record packed to 8B:
// w0 = src(17) | u0q[14:0]<<17 ; w1 = u0q[18:15] | u1q<<4 | dst_low9<<23   (u at 19 bits)
__global__ __launch_bounds__(256) void k_part(const int* __restrict__ src,
                                              const int* __restrict__ dst,
                                              const float2* __restrict__ ea,
                                              const int* __restrict__ histM,
                                              const int* __restrict__ cbase,
                                              uint2* __restrict__ Es) {
    __shared__ int cur[NC];
    for (int i = threadIdx.x; i < NC; i += 256)
        cur[i] = cbase[i] + histM[i * PBLK + blockIdx.x];
    __syncthreads();
    int base = blockIdx.x * CHUNK;
    for (int i = threadIdx.x; i < CHUNK; i += 256) {
        int e = base + i;
        int d = dst[e];
        float2 u = ea[e];
        float u0 = fminf(fmaxf(u.x, 0.f), 1.f);
        float u1 = fminf(fmaxf(u.y, 0.f), 1.f);
        unsigned u0q = __float2uint_rn(u0 * 524287.f);
        unsigned u1q = __float2uint_rn(u1 * 524287.f);
        unsigned w0 = (unsigned)src[e] | ((u0q & 0x7FFFu) << 17);
        unsigned w1 = (u0q >> 15) | (u1q << 4) | ((unsigned)(d & 511) << 23);
        int pos = atomicAdd(&cur[d >> 9], 1);
        Es[pos] = make_uint2(w0, w1);
    }
}

// per coarse bucket: 512-node LDS histogram -> scan -> rowptr -> scatter into CSR window
__global__ __launch_bounds__(256) void k_fine(const uint2* __restrict__ Es,
                                              const int* __restrict__ cbase,
                                              int* __restrict__ rowptr,
                                              uint2* __restrict__ Ep) {
    __shared__ int cnt[512];
    __shared__ int cur[512];
    __shared__ int sd[256];
    int b = blockIdx.x, t = threadIdx.x;
    int lo = cbase[b], hi = cbase[b + 1];
    cnt[t] = 0; cnt[t + 256] = 0;
    __syncthreads();
    for (int i = lo + t; i < hi; i += 256)
        atomicAdd(&cnt[Es[i].y >> 23], 1);
    __syncthreads();
    int c0 = cnt[2 * t], c1 = cnt[2 * t + 1];
    int tsum = c0 + c1;
    sd[t] = tsum;
    __syncthreads();
    for (int off = 1; off < 256; off <<= 1) {
        int x = (t >= off) ? sd[t - off] : 0;
        __syncthreads();
        sd[t] += x;
        __syncthreads();
    }
    int excl = sd[t] - tsum + lo;
    cur[2 * t] = excl;
    cur[2 * t + 1] = excl + c0;
    int n = b * 512 + 2 * t;
    if (n < N_NODES) rowptr[n] = excl;
    if (n + 1 < N_NODES) rowptr[n + 1] = excl + c0;
    if (b == NC - 1 && t == 0) rowptr[N_NODES] = N_EDGES;
    __syncthreads();
    for (int i = lo + t; i < hi; i += 256) {
        uint2 r = Es[i];
        int pos = atomicAdd(&cur[r.y >> 23], 1);
        Ep[pos] = r;
    }
}

#define DECODE_EDGE(r)                                              \
    int s = r.x & 0x1FFFF;                                          \
    unsigned u0q = (r.x >> 17) | ((r.y & 0xFu) << 15);              \
    unsigned u1q = (r.y >> 4) & 0x7FFFFu;                           \
    float u0 = u0q * (1.f / 524287.f);                              \
    float u1 = u1q * (1.f / 524287.f);                              \
    float nu0 = 1.f - u0, nu1 = 1.f - u1;                           \
    float b0 = nu0 * nu1, b1 = u0 * nu1, b2 = nu0 * u1, b3 = u0 * u1;

// ---------------- layer 1: CIN=3, COUT=8, no input BN; 8-way edge split ----------------
__global__ __launch_bounds__(256) void layer1_kernel(const float* __restrict__ xin,
                                                     const int* __restrict__ rowptr,
                                                     const uint2* __restrict__ Ep,
                                                     const float* __restrict__ W,
                                                     float* __restrict__ tout) {
    __shared__ float Wl[96];               // [k][c][d] flat, same as global
    for (int i = threadIdx.x; i < 96; i += 256) Wl[i] = W[i];
    __syncthreads();
    int lane8 = threadIdx.x & 7;
    int n = blockIdx.x * 32 + (threadIdx.x >> 3);
    int e0 = rowptr[n], e1 = rowptr[n + 1];
    float z[12];
#pragma unroll
    for (int i = 0; i < 12; ++i) z[i] = 0.f;
#pragma unroll 2
    for (int j = e0 + lane8; j < e1; j += 8) {
        uint2 r = Ep[j];
        DECODE_EDGE(r)
        float x0 = xin[s * 3 + 0], x1 = xin[s * 3 + 1], x2 = xin[s * 3 + 2];
        z[0] += b0 * x0; z[1]  += b0 * x1; z[2]  += b0 * x2;
        z[3] += b1 * x0; z[4]  += b1 * x1; z[5]  += b1 * x2;
        z[6] += b2 * x0; z[7]  += b2 * x1; z[8]  += b2 * x2;
        z[9] += b3 * x0; z[10] += b3 * x1; z[11] += b3 * x2;
    }
#pragma unroll
    for (int i = 0; i < 12; ++i) {
        z[i] += __shfl_xor(z[i], 4);
        z[i] += __shfl_xor(z[i], 2);
        z[i] += __shfl_xor(z[i], 1);
    }
    float y = 0.f;
#pragma unroll
    for (int kc = 0; kc < 12; ++kc) y += z[kc] * Wl[kc * 8 + lane8];
    float invd = 1.f / fmaxf((float)(e1 - e0), 1.f);
    float v = y * invd;
    tout[(size_t)n * 8 + lane8] = v > 0.f ? v : expm1f(v);
}

// ---------------- layer 2: CIN=8, COUT=16; 4-way edge split, c-half by kq&1 ----------------
__global__ __launch_bounds__(256) void layer2_kernel(const float* __restrict__ xin,
                                                     const float* __restrict__ scsh,
                                                     const int* __restrict__ rowptr,
                                                     const uint2* __restrict__ Ep,
                                                     const float* __restrict__ W,
                                                     float* __restrict__ tout) {
    __shared__ float4 Wl[140];             // f2 = k*35 + d4p*9 + c   (sc folded)
    __shared__ float shW[64];              // [k][16] = sum_c sh[c]*W[k][c][d]
    int t = threadIdx.x;
    if (t < 128) {
        int k = t >> 5, d4 = (t >> 3) & 3, c = t & 7;
        float4 w = ((const float4*)W)[(k * 8 + c) * 4 + d4];
        float s = scsh[c];
        Wl[k * 35 + d4 * 9 + c] = make_float4(w.x * s, w.y * s, w.z * s, w.w * s);
    } else if (t < 192) {
        int j = t - 128;
        int k = j >> 4, d = j & 15;
        float acc = 0.f;
#pragma unroll
        for (int c = 0; c < 8; ++c) acc += scsh[8 + c] * W[(k * 8 + c) * 16 + d];
        shW[j] = acc;
    }
    __syncthreads();

    int lane8 = t & 7;
    int kq = lane8 & 3, h = lane8 >> 2;
    int ch = kq & 1;                       // c-half
    int eo = lane8 >> 1;                   // edge offset 0..3 (bits kq1,h)
    int n = blockIdx.x * 32 + (t >> 3);
    int e0 = rowptr[n], e1 = rowptr[n + 1];
    float z[16], S[4];
#pragma unroll
    for (int i = 0; i < 16; ++i) z[i] = 0.f;
#pragma unroll
    for (int i = 0; i < 4; ++i) S[i] = 0.f;
#pragma unroll 2
    for (int j = e0 + eo; j < e1; j += 4) {
        uint2 r = Ep[j];
        DECODE_EDGE(r)
        float4 v = *(const float4*)(xin + (size_t)s * 8 + 4 * ch);
        S[0] += b0; S[1] += b1; S[2] += b2; S[3] += b3;
        z[0]  += b0 * v.x; z[1]  += b0 * v.y; z[2]  += b0 * v.z; z[3]  += b0 * v.w;
        z[4]  += b1 * v.x; z[5]  += b1 * v.y; z[6]  += b1 * v.z; z[7]  += b1 * v.w;
        z[8]  += b2 * v.x; z[9]  += b2 * v.y; z[10] += b2 * v.z; z[11] += b2 * v.w;
        z[12] += b3 * v.x; z[13] += b3 * v.y; z[14] += b3 * v.z; z[15] += b3 * v.w;
    }
    // edge-subset reduce (masks 4 then 2)
#pragma unroll
    for (int i = 0; i < 16; ++i) { z[i] += __shfl_xor(z[i], 4); z[i] += __shfl_xor(z[i], 2); }
#pragma unroll
    for (int i = 0; i < 4; ++i)  { S[i] += __shfl_xor(S[i], 4); S[i] += __shfl_xor(S[i], 2); }

    // y-partial: d-half by h, c-half by ch
    int laneW = 18 * h + 4 * ch;
    float y[8];
#pragma unroll
    for (int i = 0; i < 8; ++i) y[i] = 0.f;
#pragma unroll
    for (int k = 0; k < 4; ++k)
#pragma unroll
        for (int i = 0; i < 4; ++i) {
            float zc = z[k * 4 + i];
            int base = k * 35 + i + laneW;
#pragma unroll
            for (int d4 = 0; d4 < 2; ++d4) {
                float4 w = Wl[base + 9 * d4];
                y[4 * d4 + 0] += zc * w.x; y[4 * d4 + 1] += zc * w.y;
                y[4 * d4 + 2] += zc * w.z; y[4 * d4 + 3] += zc * w.w;
            }
        }
    // mask-1: sum c-halves, keep d-quarter by ch (static select)
    float y1[4];
#pragma unroll
    for (int i = 0; i < 4; ++i) {
        float a = y[i]     + __shfl_xor(y[i],     1);
        float b = y[4 + i] + __shfl_xor(y[4 + i], 1);
        y1[i] = ch ? b : a;
    }
    int qb = (kq >> 1) & 1;
    float f0 = qb ? y1[2] : y1[0];
    float f1 = qb ? y1[3] : y1[1];
    int d = h * 8 + ch * 4 + qb * 2;
    f0 += S[0] * shW[d]     + S[1] * shW[16 + d]     + S[2] * shW[32 + d]     + S[3] * shW[48 + d];
    f1 += S[0] * shW[d + 1] + S[1] * shW[16 + d + 1] + S[2] * shW[32 + d + 1] + S[3] * shW[48 + d + 1];
    float invd = 1.f / fmaxf((float)(e1 - e0), 1.f);
    f0 *= invd; f1 *= invd;
    f0 = f0 > 0.f ? f0 : expm1f(f0);
    f1 = f1 > 0.f ? f1 : expm1f(f1);
    *(float2*)(tout + (size_t)n * 16 + d) = make_float2(f0, f1);
}

// ---------------- layer 3: CIN=16, COUT=32; 2-way edge split, c-quarter by kq ----------------
__global__ __launch_bounds__(256) void layer3_kernel(const float* __restrict__ xin,
                                                     const float* __restrict__ scsh,
                                                     const int* __restrict__ rowptr,
                                                     const uint2* __restrict__ Ep,
                                                     const float* __restrict__ W,
                                                     float* __restrict__ tout) {
    __shared__ float4 Wl[580];             // f3 = k*145 + d4p*18 + (d4p>>2) + c + 2*(c>>3)
    __shared__ float shW[128];             // [k][32]
    int t = threadIdx.x;
    for (int i = t; i < 512; i += 256) {
        int k = i >> 7, d4 = (i >> 4) & 7, c = i & 15;
        float4 w = ((const float4*)W)[(k * 16 + c) * 8 + d4];
        float s = scsh[c];
        Wl[k * 145 + d4 * 18 + (d4 >> 2) + c + 2 * (c >> 3)] =
            make_float4(w.x * s, w.y * s, w.z * s, w.w * s);
    }
    if (t < 128) {
        int k = t >> 5, d = t & 31;
        float acc = 0.f;
#pragma unroll
        for (int c = 0; c < 16; ++c) acc += scsh[16 + c] * W[(k * 16 + c) * 32 + d];
        shW[t] = acc;
    }
    __syncthreads();

    int lane8 = t & 7;
    int kq = lane8 & 3, h = lane8 >> 2;
    int n = blockIdx.x * 32 + (t >> 3);
    int e0 = rowptr[n], e1 = rowptr[n + 1];
    float z[16], S[4];
#pragma unroll
    for (int i = 0; i < 16; ++i) z[i] = 0.f;
#pragma unroll
    for (int i = 0; i < 4; ++i) S[i] = 0.f;
#pragma unroll 2
    for (int j = e0 + h; j < e1; j += 2) {
        uint2 r = Ep[j];
        DECODE_EDGE(r)
        float4 v = *(const float4*)(xin + (size_t)s * 16 + 4 * kq);   // this lane's quarter
        S[0] += b0; S[1] += b1; S[2] += b2; S[3] += b3;
        z[0]  += b0 * v.x; z[1]  += b0 * v.y; z[2]  += b0 * v.z; z[3]  += b0 * v.w;
        z[4]  += b1 * v.x; z[5]  += b1 * v.y; z[6]  += b1 * v.z; z[7]  += b1 * v.w;
        z[8]  += b2 * v.x; z[9]  += b2 * v.y; z[10] += b2 * v.z; z[11] += b2 * v.w;
        z[12] += b3 * v.x; z[13] += b3 * v.y; z[14] += b3 * v.z; z[15] += b3 * v.w;
    }
    // h-reduce (edge halves)
#pragma unroll
    for (int i = 0; i < 16; ++i) z[i] += __shfl_xor(z[i], 4);
#pragma unroll
    for (int i = 0; i < 4; ++i)  S[i] += __shfl_xor(S[i], 4);

    // y-partial: d-half by h, c-quarter by kq  (bank-swizzled W reads)
    int laneW = 4 * kq + 2 * (kq >> 1) + 73 * h;
    float y[16];
#pragma unroll
    for (int i = 0; i < 16; ++i) y[i] = 0.f;
#pragma unroll
    for (int k = 0; k < 4; ++k)
#pragma unroll
        for (int i = 0; i < 4; ++i) {
            float zc = z[k * 4 + i];
            int base = k * 145 + i + laneW;
#pragma unroll
            for (int d4 = 0; d4 < 4; ++d4) {
                float4 w = Wl[base + 18 * d4];
                y[4 * d4 + 0] += zc * w.x; y[4 * d4 + 1] += zc * w.y;
                y[4 * d4 + 2] += zc * w.z; y[4 * d4 + 3] += zc * w.w;
            }
        }
    // select-tree reduce over c-quarters (masks 1 then 2), static indices
    float y1[8];
#pragma unroll
    for (int i = 0; i < 8; ++i) {
        float a = y[i]     + __shfl_xor(y[i],     1);
        float b = y[8 + i] + __shfl_xor(y[8 + i], 1);
        y1[i] = (kq & 1) ? b : a;
    }
    float y2[4];
#pragma unroll
    for (int i = 0; i < 4; ++i) {
        float a = y1[i]     + __shfl_xor(y1[i],     2);
        float b = y1[4 + i] + __shfl_xor(y1[4 + i], 2);
        y2[i] = (kq & 2) ? b : a;
    }
    int d = h * 16 + (kq & 1) * 8 + ((kq >> 1) & 1) * 4;
#pragma unroll
    for (int i = 0; i < 4; ++i)
        y2[i] += S[0] * shW[d + i] + S[1] * shW[32 + d + i] +
                 S[2] * shW[64 + d + i] + S[3] * shW[96 + d + i];
    float invd = 1.f / fmaxf((float)(e1 - e0), 1.f);
#pragma unroll
    for (int i = 0; i < 4; ++i) {
        float v = y2[i] * invd;
        y2[i] = v > 0.f ? v : expm1f(v);
    }
    *(float4*)(tout + (size_t)n * 32 + d) = make_float4(y2[0], y2[1], y2[2], y2[3]);
}

// ---------------- BN stats + finalize ----------------
template <int COUT>
__global__ __launch_bounds__(256) void bnstats_kernel(const float* __restrict__ t,
                                                      float* __restrict__ sums) {
    constexpr int ROWS = 256 / COUT;
    int ch = threadIdx.x % COUT;
    int r = threadIdx.x / COUT;
    float s = 0.f, q = 0.f;
    for (int n = blockIdx.x * ROWS + r; n < N_NODES; n += gridDim.x * ROWS) {
        float v = t[(size_t)n * COUT + ch];
        s += v;
        q += v * v;
    }
    __shared__ float ls[256], lq[256];
    ls[threadIdx.x] = s; lq[threadIdx.x] = q;
    __syncthreads();
    for (int off = 128; off >= COUT; off >>= 1) {
        if (threadIdx.x < off) {
            ls[threadIdx.x] += ls[threadIdx.x + off];
            lq[threadIdx.x] += lq[threadIdx.x + off];
        }
        __syncthreads();
    }
    if (threadIdx.x < COUT) {
        atomicAdd(&sums[ch], ls[threadIdx.x]);
        atomicAdd(&sums[COUT + ch], lq[threadIdx.x]);
    }
}

template <int COUT>
__global__ void bnfin_kernel(const float* __restrict__ sums, const float* __restrict__ g,
                             const float* __restrict__ b, float* __restrict__ scsh) {
    int ch = threadIdx.x;
    if (ch >= COUT) return;
    float mu = sums[ch] * (1.f / N_NODES);
    float var = fmaxf(sums[COUT + ch] * (1.f / N_NODES) - mu * mu, 0.f);
    float rs = 1.f / sqrtf(var + 1e-5f);
    float s = g[ch] * rs;
    scsh[ch] = s;
    scsh[COUT + ch] = b[ch] - mu * s;
}

// ---------------- pooling (batch is sorted) + FC ----------------
__global__ __launch_bounds__(256) void pool_kernel(const float* __restrict__ t3,
                                                   const int* __restrict__ batch,
                                                   float* __restrict__ pooled) {
    __shared__ float tile[256][33];
    __shared__ int lb[256];
    int n = blockIdx.x * 256 + threadIdx.x;
    int valid = N_NODES - blockIdx.x * 256;
    if (valid > 256) valid = 256;
    if (n < N_NODES) {
        const float4* r = (const float4*)(t3 + (size_t)n * 32);
#pragma unroll
        for (int i = 0; i < 8; ++i) {
            float4 v = r[i];
            tile[threadIdx.x][4 * i + 0] = v.x;
            tile[threadIdx.x][4 * i + 1] = v.y;
            tile[threadIdx.x][4 * i + 2] = v.z;
            tile[threadIdx.x][4 * i + 3] = v.w;
        }
        lb[threadIdx.x] = batch[n];
    }
    __syncthreads();
    if (threadIdx.x < 32) {
        int ch = threadIdx.x;
        float run = 0.f;
        int gp = lb[0];
        for (int r = 0; r < valid; ++r) {
            int g = lb[r];
            if (g != gp) {
                atomicAdd(&pooled[gp * 32 + ch], run);
                run = 0.f;
                gp = g;
            }
            run += tile[r][ch];
        }
        atomicAdd(&pooled[gp * 32 + ch], run);
    }
}

__global__ void final_kernel(const float* __restrict__ pooled, const int* __restrict__ cntg,
                             const float* __restrict__ scsh3, const float* __restrict__ fcw,
                             float* __restrict__ out) {
    int i = threadIdx.x;
    if (i >= N_GRAPHS * 10) return;
    int g = i / 10, o = i % 10;
    float rc = 1.f / fmaxf((float)cntg[g], 1.f);
    float acc = 0.f;
#pragma unroll
    for (int d = 0; d < 32; ++d) {
        float pm = scsh3[d] * (pooled[g * 32 + d] * rc) + scsh3[32 + d];
        acc += pm * fcw[o * 32 + d];
    }
    out[i] = acc;
}

extern "C" void kernel_launch(void* const* d_in, const int* in_sizes, int n_in,
                              void* d_out, int out_size, void* d_ws, size_t ws_size,
                              hipStream_t stream) {
    const float* x   = (const float*)d_in[0];
    const int*   ei  = (const int*)d_in[1];
    const float* ea  = (const float*)d_in[2];
    const int*   bat = (const int*)d_in[3];
    const float* W1  = (const float*)d_in[4];
    const float* W2  = (const float*)d_in[5];
    const float* W3  = (const float*)d_in[6];
    const float* g1  = (const float*)d_in[7];
    const float* b1  = (const float*)d_in[8];
    const float* g2  = (const float*)d_in[9];
    const float* b2  = (const float*)d_in[10];
    const float* g3  = (const float*)d_in[11];
    const float* b3  = (const float*)d_in[12];
    const float* fcw = (const float*)d_in[13];
    float* out = (float*)d_out;
    char* ws = (char*)d_ws;

    int*    cntg   = (int*)(ws + OFF_CNTG);
    float*  bns1   = (float*)(ws + OFF_BNS1);
    float*  bns2   = (float*)(ws + OFF_BNS2);
    float*  bns3   = (float*)(ws + OFF_BNS3);
    float*  pooled = (float*)(ws + OFF_POOLED);
    float*  scsh1  = (float*)(ws + OFF_SCSH1);
    float*  scsh2  = (float*)(ws + OFF_SCSH2);
    float*  scsh3  = (float*)(ws + OFF_SCSH3);
    int*    cbase  = (int*)(ws + OFF_CBASE);
    int*    btot   = (int*)(ws + OFF_BTOT);
    int*    rowptr = (int*)(ws + OFF_ROWPTR);
    int*    histM  = (int*)(ws + OFF_HISTM);
    uint2*  Es     = (uint2*)(ws + OFF_ES);
    uint2*  Ep     = (uint2*)(ws + OFF_EP);
    float*  t1     = (float*)(ws + OFF_T1);
    float*  t2     = (float*)(ws + OFF_T2);
    float*  t3     = (float*)(ws + OFF_T3);

    const int* src = ei;
    const int* dst = ei + N_EDGES;

    hipMemsetAsync(ws, 0, ZERO_BYTES, stream);

    cnt_kernel<<<1, 64, 0, stream>>>(bat, cntg);
    k_hist<<<PBLK, 256, 0, stream>>>(dst, histM);
    k_scan1<<<NC, 256, 0, stream>>>(histM, btot);
    k_scan2<<<1, 256, 0, stream>>>(btot, cbase);
    k_part<<<PBLK, 256, 0, stream>>>(src, dst, (const float2*)ea, histM, cbase, Es);
    k_fine<<<NC, 256, 0, stream>>>(Es, cbase, rowptr, Ep);

    layer1_kernel<<<LBLK, 256, 0, stream>>>(x, rowptr, Ep, W1, t1);
    bnstats_kernel<8><<<256, 256, 0, stream>>>(t1, bns1);
    bnfin_kernel<8><<<1, 32, 0, stream>>>(bns1, g1, b1, scsh1);

    layer2_kernel<<<LBLK, 256, 0, stream>>>(t1, scsh1, rowptr, Ep, W2, t2);
    bnstats_kernel<16><<<256, 256, 0, stream>>>(t2, bns2);
    bnfin_kernel<16><<<1, 32, 0, stream>>>(bns2, g2, b2, scsh2);

    layer3_kernel<<<LBLK, 256, 0, stream>>>(t2, scsh2, rowptr, Ep, W3, t3);
    bnstats_kernel<32><<<256, 256, 0, stream>>>(t3, bns3);
    bnfin_kernel<32><<<1, 32, 0, stream>>>(bns3, g3, b3, scsh3);

    pool_kernel<<<NBLK, 256, 0, stream>>>(t3, bat, pooled);
    final_kernel<<<1, 640, 0, stream>>>(pooled, cntg, scsh3, fcw, out);
}

// Round 8
// 254.261 us; speedup vs baseline: 1.0829x; 1.0829x over previous
//
#include <hip/hip_runtime.h>
#include <hip/hip_fp16.h>

#define N_NODES 100000
#define N_EDGES 3200000
#define N_GRAPHS 64
constexpr int NC    = 196;                 // coarse buckets of 512 nodes (196*512=100352)
constexpr int PBLK  = 256;                 // partition blocks
constexpr int CHUNK = N_EDGES / PBLK;      // 12500 edges/block (exact)
constexpr int NBLK  = (N_NODES + 255) / 256;
constexpr int LBLK  = N_NODES / 32;        // 3125 exact: 32 nodes/block, 8 lanes/node
#define EPS 1e-5f

// ---- workspace layout (bytes) ----
constexpr size_t OFF_CNTG   = 0x0;         // int[64]
constexpr size_t OFF_BNS1   = 0x400;       // float[16]
constexpr size_t OFF_BNS2   = 0x500;       // float[32]
constexpr size_t OFF_BNS3   = 0x700;       // float[64]
constexpr size_t OFF_POOLED = 0x1000;      // float[64*32] = 8KB
constexpr size_t ZERO_BYTES = 0x3000;      // memset [0, here)
constexpr size_t OFF_CBASE  = 0x4000;      // int[NC+1]
constexpr size_t OFF_BTOT   = 0x5000;      // int[NC]
constexpr size_t OFF_ROWPTR = 0x10000;     // int[N_NODES+1]
constexpr size_t OFF_HISTM  = 0x80000;     // int[NC*PBLK] ~200KB
constexpr size_t OFF_ES     = 0x200000;    // uint2[N_EDGES] 25.6MB (staging)
constexpr size_t OFF_EP     = 0x1B00000;   // uint2[N_EDGES] 25.6MB (CSR)
constexpr size_t OFF_T1     = 0x3400000;   // half[N_NODES*8]  1.6MB
constexpr size_t OFF_T2     = 0x3800000;   // half[N_NODES*16] 3.2MB
constexpr size_t OFF_T3     = 0x4000000;   // half[N_NODES*32] 6.4MB

// batch is sorted -> per-graph count via binary search (no atomics)
__global__ void cnt_kernel(const int* __restrict__ batch, int* __restrict__ cntg) {
    int g = threadIdx.x;
    if (g >= N_GRAPHS) return;
    int lo0 = 0, hi0 = N_NODES;
    while (lo0 < hi0) { int m = (lo0 + hi0) >> 1; if (batch[m] < g) lo0 = m + 1; else hi0 = m; }
    int lo1 = lo0, hi1 = N_NODES;
    while (lo1 < hi1) { int m = (lo1 + hi1) >> 1; if (batch[m] < g + 1) lo1 = m + 1; else hi1 = m; }
    cntg[g] = lo1 - lo0;
}

// per-block LDS coarse-bucket histogram (no global atomics)
__global__ __launch_bounds__(256) void k_hist(const int* __restrict__ dst,
                                              int* __restrict__ histM) {
    __shared__ int h[NC];
    for (int i = threadIdx.x; i < NC; i += 256) h[i] = 0;
    __syncthreads();
    int base = blockIdx.x * CHUNK;
    for (int i = threadIdx.x; i < CHUNK; i += 256)
        atomicAdd(&h[dst[base + i] >> 9], 1);
    __syncthreads();
    for (int i = threadIdx.x; i < NC; i += 256)
        histM[i * PBLK + blockIdx.x] = h[i];
}

// per-bucket exclusive scan over blocks; emit bucket totals
__global__ __launch_bounds__(256) void k_scan1(int* __restrict__ histM,
                                               int* __restrict__ btot) {
    __shared__ int sd[256];
    int b = blockIdx.x, t = threadIdx.x;
    int v = histM[b * PBLK + t];
    sd[t] = v;
    __syncthreads();
    for (int off = 1; off < 256; off <<= 1) {
        int x = (t >= off) ? sd[t - off] : 0;
        __syncthreads();
        sd[t] += x;
        __syncthreads();
    }
    histM[b * PBLK + t] = sd[t] - v;   // exclusive within bucket
    if (t == 255) btot[b] = sd[255];
}

// exclusive scan over bucket totals -> coarse bucket bases
__global__ __launch_bounds__(256) void k_scan2(const int* __restrict__ btot,
                                               int* __restrict__ cbase) {
    __shared__ int sd[256];
    int t = threadIdx.x;
    int v = (t < NC) ? btot[t] : 0;
    sd[t] = v;
    __syncthreads();
    for (int off = 1; off < 256; off <<= 1) {
        int x = (t >= off) ? sd[t - off] : 0;
        __syncthreads();
        sd[t] += x;
        __syncthreads();
    }
    if (t < NC) cbase[t] = sd[t] - v;
    if (t == 0) cbase[NC] = N_EDGES;
}

// partition edges into coarse-bucket sub-streams; record packed to 8B:
// w0 = src(17) | u0q[14:0]<<17 ; w1 = u0q[18:15] | u1q<<4 | dst_low9<<23   (u at 19 bits)
__global__ __launch_bounds__(256) void k_part(const int* __restrict__ src,
                                              const int* __restrict__ dst,
                                              const float2* __restrict__ ea,
                                              const int* __restrict__ histM,
                                              const int* __restrict__ cbase,
                                              uint2* __restrict__ Es) {
    __shared__ int cur[NC];
    for (int i = threadIdx.x; i < NC; i += 256)
        cur[i] = cbase[i] + histM[i * PBLK + blockIdx.x];
    __syncthreads();
    int base = blockIdx.x * CHUNK;
    for (int i = threadIdx.x; i < CHUNK; i += 256) {
        int e = base + i;
        int d = dst[e];
        float2 u = ea[e];
        float u0 = fminf(fmaxf(u.x, 0.f), 1.f);
        float u1 = fminf(fmaxf(u.y, 0.f), 1.f);
        unsigned u0q = __float2uint_rn(u0 * 524287.f);
        unsigned u1q = __float2uint_rn(u1 * 524287.f);
        unsigned w0 = (unsigned)src[e] | ((u0q & 0x7FFFu) << 17);
        unsigned w1 = (u0q >> 15) | (u1q << 4) | ((unsigned)(d & 511) << 23);
        int pos = atomicAdd(&cur[d >> 9], 1);
        Es[pos] = make_uint2(w0, w1);
    }
}

// per coarse bucket: 512-node LDS histogram -> scan -> rowptr -> scatter into CSR window
__global__ __launch_bounds__(256) void k_fine(const uint2* __restrict__ Es,
                                              const int* __restrict__ cbase,
                                              int* __restrict__ rowptr,
                                              uint2* __restrict__ Ep) {
    __shared__ int cnt[512];
    __shared__ int cur[512];
    __shared__ int sd[256];
    int b = blockIdx.x, t = threadIdx.x;
    int lo = cbase[b], hi = cbase[b + 1];
    cnt[t] = 0; cnt[t + 256] = 0;
    __syncthreads();
    for (int i = lo + t; i < hi; i += 256)
        atomicAdd(&cnt[Es[i].y >> 23], 1);
    __syncthreads();
    int c0 = cnt[2 * t], c1 = cnt[2 * t + 1];
    int tsum = c0 + c1;
    sd[t] = tsum;
    __syncthreads();
    for (int off = 1; off < 256; off <<= 1) {
        int x = (t >= off) ? sd[t - off] : 0;
        __syncthreads();
        sd[t] += x;
        __syncthreads();
    }
    int excl = sd[t] - tsum + lo;
    cur[2 * t] = excl;
    cur[2 * t + 1] = excl + c0;
    int n = b * 512 + 2 * t;
    if (n < N_NODES) rowptr[n] = excl;
    if (n + 1 < N_NODES) rowptr[n + 1] = excl + c0;
    if (b == NC - 1 && t == 0) rowptr[N_NODES] = N_EDGES;
    __syncthreads();
    for (int i = lo + t; i < hi; i += 256) {
        uint2 r = Es[i];
        int pos = atomicAdd(&cur[r.y >> 23], 1);
        Ep[pos] = r;
    }
}

#define DECODE_EDGE(r)                                              \
    int s = r.x & 0x1FFFF;                                          \
    unsigned u0q = (r.x >> 17) | ((r.y & 0xFu) << 15);              \
    unsigned u1q = (r.y >> 4) & 0x7FFFFu;                           \
    float u0 = u0q * (1.f / 524287.f);                              \
    float u1 = u1q * (1.f / 524287.f);                              \
    float nu0 = 1.f - u0, nu1 = 1.f - u1;                           \
    float b0 = nu0 * nu1, b1 = u0 * nu1, b2 = nu0 * u1, b3 = u0 * u1;

// ---------------- layer 1: CIN=3, COUT=8, fp32 in, fp16 out; 8-way edge split ----------------
__global__ __launch_bounds__(256) void layer1_kernel(const float* __restrict__ xin,
                                                     const int* __restrict__ rowptr,
                                                     const uint2* __restrict__ Ep,
                                                     const float* __restrict__ W,
                                                     __half* __restrict__ tout) {
    __shared__ float Wl[96];               // [k][c][d] flat, same as global
    for (int i = threadIdx.x; i < 96; i += 256) Wl[i] = W[i];
    __syncthreads();
    int lane8 = threadIdx.x & 7;
    int n = blockIdx.x * 32 + (threadIdx.x >> 3);
    int e0 = rowptr[n], e1 = rowptr[n + 1];
    float z[12];
#pragma unroll
    for (int i = 0; i < 12; ++i) z[i] = 0.f;
#pragma unroll 2
    for (int j = e0 + lane8; j < e1; j += 8) {
        uint2 r = Ep[j];
        DECODE_EDGE(r)
        float x0 = xin[s * 3 + 0], x1 = xin[s * 3 + 1], x2 = xin[s * 3 + 2];
        z[0] += b0 * x0; z[1]  += b0 * x1; z[2]  += b0 * x2;
        z[3] += b1 * x0; z[4]  += b1 * x1; z[5]  += b1 * x2;
        z[6] += b2 * x0; z[7]  += b2 * x1; z[8]  += b2 * x2;
        z[9] += b3 * x0; z[10] += b3 * x1; z[11] += b3 * x2;
    }
#pragma unroll
    for (int i = 0; i < 12; ++i) {
        z[i] += __shfl_xor(z[i], 4);
        z[i] += __shfl_xor(z[i], 2);
        z[i] += __shfl_xor(z[i], 1);
    }
    float y = 0.f;
#pragma unroll
    for (int kc = 0; kc < 12; ++kc) y += z[kc] * Wl[kc * 8 + lane8];
    float invd = 1.f / fmaxf((float)(e1 - e0), 1.f);
    float v = y * invd;
    v = v > 0.f ? v : expm1f(v);
    tout[(size_t)n * 8 + lane8] = __float2half_rn(v);
}

// ------- layer 2: CIN=8, COUT=16; fp16 in/out; BN folded from sums (no bnfin) -------
__global__ __launch_bounds__(256) void layer2_kernel(const __half* __restrict__ xin,
                                                     const float* __restrict__ bns,
                                                     const float* __restrict__ g,
                                                     const float* __restrict__ bb,
                                                     const int* __restrict__ rowptr,
                                                     const uint2* __restrict__ Ep,
                                                     const float* __restrict__ W,
                                                     __half* __restrict__ tout) {
    __shared__ float scA[8], shA[8];
    __shared__ float4 Wl[140];             // f2 = k*35 + d4p*9 + c   (sc folded)
    __shared__ float shW[64];              // [k][16] = sum_c sh[c]*W[k][c][d]
    int t = threadIdx.x;
    if (t < 8) {
        float mu = bns[t] * (1.f / N_NODES);
        float var = fmaxf(bns[8 + t] * (1.f / N_NODES) - mu * mu, 0.f);
        float s = g[t] * rsqrtf(var + EPS);
        scA[t] = s;
        shA[t] = bb[t] - mu * s;
    }
    __syncthreads();
    if (t < 128) {
        int k = t >> 5, d4 = (t >> 3) & 3, c = t & 7;
        float4 w = ((const float4*)W)[(k * 8 + c) * 4 + d4];
        float s = scA[c];
        Wl[k * 35 + d4 * 9 + c] = make_float4(w.x * s, w.y * s, w.z * s, w.w * s);
    } else if (t < 192) {
        int j = t - 128;
        int k = j >> 4, d = j & 15;
        float acc = 0.f;
#pragma unroll
        for (int c = 0; c < 8; ++c) acc += shA[c] * W[(k * 8 + c) * 16 + d];
        shW[j] = acc;
    }
    __syncthreads();

    int lane8 = t & 7;
    int kq = lane8 & 3, h = lane8 >> 2;
    int ch = kq & 1;                       // c-half
    int eo = lane8 >> 1;                   // edge offset 0..3 (bits kq1,h)
    int n = blockIdx.x * 32 + (t >> 3);
    int e0 = rowptr[n], e1 = rowptr[n + 1];
    float z[16], S[4];
#pragma unroll
    for (int i = 0; i < 16; ++i) z[i] = 0.f;
#pragma unroll
    for (int i = 0; i < 4; ++i) S[i] = 0.f;
#pragma unroll 2
    for (int j = e0 + eo; j < e1; j += 4) {
        uint2 r = Ep[j];
        DECODE_EDGE(r)
        uint2 hv = *(const uint2*)(xin + (size_t)s * 8 + 4 * ch);
        float2 f0 = __half22float2(*(__half2*)&hv.x);
        float2 f1 = __half22float2(*(__half2*)&hv.y);
        S[0] += b0; S[1] += b1; S[2] += b2; S[3] += b3;
        z[0]  += b0 * f0.x; z[1]  += b0 * f0.y; z[2]  += b0 * f1.x; z[3]  += b0 * f1.y;
        z[4]  += b1 * f0.x; z[5]  += b1 * f0.y; z[6]  += b1 * f1.x; z[7]  += b1 * f1.y;
        z[8]  += b2 * f0.x; z[9]  += b2 * f0.y; z[10] += b2 * f1.x; z[11] += b2 * f1.y;
        z[12] += b3 * f0.x; z[13] += b3 * f0.y; z[14] += b3 * f1.x; z[15] += b3 * f1.y;
    }
    // edge-subset reduce (masks 4 then 2)
#pragma unroll
    for (int i = 0; i < 16; ++i) { z[i] += __shfl_xor(z[i], 4); z[i] += __shfl_xor(z[i], 2); }
#pragma unroll
    for (int i = 0; i < 4; ++i)  { S[i] += __shfl_xor(S[i], 4); S[i] += __shfl_xor(S[i], 2); }

    // y-partial: d-half by h, c-half by ch
    int laneW = 18 * h + 4 * ch;
    float y[8];
#pragma unroll
    for (int i = 0; i < 8; ++i) y[i] = 0.f;
#pragma unroll
    for (int k = 0; k < 4; ++k)
#pragma unroll
        for (int i = 0; i < 4; ++i) {
            float zc = z[k * 4 + i];
            int base = k * 35 + i + laneW;
#pragma unroll
            for (int d4 = 0; d4 < 2; ++d4) {
                float4 w = Wl[base + 9 * d4];
                y[4 * d4 + 0] += zc * w.x; y[4 * d4 + 1] += zc * w.y;
                y[4 * d4 + 2] += zc * w.z; y[4 * d4 + 3] += zc * w.w;
            }
        }
    // mask-1: sum c-halves, keep d-quarter by ch (static select)
    float y1[4];
#pragma unroll
    for (int i = 0; i < 4; ++i) {
        float a = y[i]     + __shfl_xor(y[i],     1);
        float b = y[4 + i] + __shfl_xor(y[4 + i], 1);
        y1[i] = ch ? b : a;
    }
    int qb = (kq >> 1) & 1;
    float f0 = qb ? y1[2] : y1[0];
    float f1 = qb ? y1[3] : y1[1];
    int d = h * 8 + ch * 4 + qb * 2;
    f0 += S[0] * shW[d]     + S[1] * shW[16 + d]     + S[2] * shW[32 + d]     + S[3] * shW[48 + d];
    f1 += S[0] * shW[d + 1] + S[1] * shW[16 + d + 1] + S[2] * shW[32 + d + 1] + S[3] * shW[48 + d + 1];
    float invd = 1.f / fmaxf((float)(e1 - e0), 1.f);
    f0 *= invd; f1 *= invd;
    f0 = f0 > 0.f ? f0 : expm1f(f0);
    f1 = f1 > 0.f ? f1 : expm1f(f1);
    *(__half2*)(tout + (size_t)n * 16 + d) = __floats2half2_rn(f0, f1);
}

// ------- layer 3: CIN=16, COUT=32; fp16 in/out; BN folded from sums (no bnfin) -------
__global__ __launch_bounds__(256) void layer3_kernel(const __half* __restrict__ xin,
                                                     const float* __restrict__ bns,
                                                     const float* __restrict__ g,
                                                     const float* __restrict__ bb,
                                                     const int* __restrict__ rowptr,
                                                     const uint2* __restrict__ Ep,
                                                     const float* __restrict__ W,
                                                     __half* __restrict__ tout) {
    __shared__ float scA[16], shA[16];
    __shared__ float4 Wl[580];             // f3 = k*145 + d4p*18 + (d4p>>2) + c + 2*(c>>3)
    __shared__ float shW[128];             // [k][32]
    int t = threadIdx.x;
    if (t < 16) {
        float mu = bns[t] * (1.f / N_NODES);
        float var = fmaxf(bns[16 + t] * (1.f / N_NODES) - mu * mu, 0.f);
        float s = g[t] * rsqrtf(var + EPS);
        scA[t] = s;
        shA[t] = bb[t] - mu * s;
    }
    __syncthreads();
    for (int i = t; i < 512; i += 256) {
        int k = i >> 7, d4 = (i >> 4) & 7, c = i & 15;
        float4 w = ((const float4*)W)[(k * 16 + c) * 8 + d4];
        float s = scA[c];
        Wl[k * 145 + d4 * 18 + (d4 >> 2) + c + 2 * (c >> 3)] =
            make_float4(w.x * s, w.y * s, w.z * s, w.w * s);
    }
    if (t < 128) {
        int k = t >> 5, d = t & 31;
        float acc = 0.f;
#pragma unroll
        for (int c = 0; c < 16; ++c) acc += shA[c] * W[(k * 16 + c) * 32 + d];
        shW[t] = acc;
    }
    __syncthreads();

    int lane8 = t & 7;
    int kq = lane8 & 3, h = lane8 >> 2;
    int n = blockIdx.x * 32 + (t >> 3);
    int e0 = rowptr[n], e1 = rowptr[n + 1];
    float z[16], S[4];
#pragma unroll
    for (int i = 0; i < 16; ++i) z[i] = 0.f;
#pragma unroll
    for (int i = 0; i < 4; ++i) S[i] = 0.f;
#pragma unroll 2
    for (int j = e0 + h; j < e1; j += 2) {
        uint2 r = Ep[j];
        DECODE_EDGE(r)
        uint2 hv = *(const uint2*)(xin + (size_t)s * 16 + 4 * kq);   // this lane's quarter
        float2 f0 = __half22float2(*(__half2*)&hv.x);
        float2 f1 = __half22float2(*(__half2*)&hv.y);
        S[0] += b0; S[1] += b1; S[2] += b2; S[3] += b3;
        z[0]  += b0 * f0.x; z[1]  += b0 * f0.y; z[2]  += b0 * f1.x; z[3]  += b0 * f1.y;
        z[4]  += b1 * f0.x; z[5]  += b1 * f0.y; z[6]  += b1 * f1.x; z[7]  += b1 * f1.y;
        z[8]  += b2 * f0.x; z[9]  += b2 * f0.y; z[10] += b2 * f1.x; z[11] += b2 * f1.y;
        z[12] += b3 * f0.x; z[13] += b3 * f0.y; z[14] += b3 * f1.x; z[15] += b3 * f1.y;
    }
    // h-reduce (edge halves)
#pragma unroll
    for (int i = 0; i < 16; ++i) z[i] += __shfl_xor(z[i], 4);
#pragma unroll
    for (int i = 0; i < 4; ++i)  S[i] += __shfl_xor(S[i], 4);

    // y-partial: d-half by h, c-quarter by kq  (bank-swizzled W reads)
    int laneW = 4 * kq + 2 * (kq >> 1) + 73 * h;
    float y[16];
#pragma unroll
    for (int i = 0; i < 16; ++i) y[i] = 0.f;
#pragma unroll
    for (int k = 0; k < 4; ++k)
#pragma unroll
        for (int i = 0; i < 4; ++i) {
            float zc = z[k * 4 + i];
            int base = k * 145 + i + laneW;
#pragma unroll
            for (int d4 = 0; d4 < 4; ++d4) {
                float4 w = Wl[base + 18 * d4];
                y[4 * d4 + 0] += zc * w.x; y[4 * d4 + 1] += zc * w.y;
                y[4 * d4 + 2] += zc * w.z; y[4 * d4 + 3] += zc * w.w;
            }
        }
    // select-tree reduce over c-quarters (masks 1 then 2), static indices
    float y1[8];
#pragma unroll
    for (int i = 0; i < 8; ++i) {
        float a = y[i]     + __shfl_xor(y[i],     1);
        float b = y[8 + i] + __shfl_xor(y[8 + i], 1);
        y1[i] = (kq & 1) ? b : a;
    }
    float y2[4];
#pragma unroll
    for (int i = 0; i < 4; ++i) {
        float a = y1[i]     + __shfl_xor(y1[i],     2);
        float b = y1[4 + i] + __shfl_xor(y1[4 + i], 2);
        y2[i] = (kq & 2) ? b : a;
    }
    int d = h * 16 + (kq & 1) * 8 + ((kq >> 1) & 1) * 4;
#pragma unroll
    for (int i = 0; i < 4; ++i)
        y2[i] += S[0] * shW[d + i] + S[1] * shW[32 + d + i] +
                 S[2] * shW[64 + d + i] + S[3] * shW[96 + d + i];
    float invd = 1.f / fmaxf((float)(e1 - e0), 1.f);
#pragma unroll
    for (int i = 0; i < 4; ++i) {
        float v = y2[i] * invd;
        y2[i] = v > 0.f ? v : expm1f(v);
    }
    __half2 h01 = __floats2half2_rn(y2[0], y2[1]);
    __half2 h23 = __floats2half2_rn(y2[2], y2[3]);
    uint2 st;
    st.x = *(unsigned*)&h01;
    st.y = *(unsigned*)&h23;
    *(uint2*)(tout + (size_t)n * 32 + d) = st;
}

// ---------------- BN stats (fp16 input, fp32 sums) ----------------
template <int COUT>
__global__ __launch_bounds__(256) void bnstats_kernel(const __half* __restrict__ t,
                                                      float* __restrict__ sums) {
    constexpr int ROWS = 256 / COUT;
    int ch = threadIdx.x % COUT;
    int r = threadIdx.x / COUT;
    float s = 0.f, q = 0.f;
    for (int n = blockIdx.x * ROWS + r; n < N_NODES; n += gridDim.x * ROWS) {
        float v = __half2float(t[(size_t)n * COUT + ch]);
        s += v;
        q += v * v;
    }
    __shared__ float ls[256], lq[256];
    ls[threadIdx.x] = s; lq[threadIdx.x] = q;
    __syncthreads();
    for (int off = 128; off >= COUT; off >>= 1) {
        if (threadIdx.x < off) {
            ls[threadIdx.x] += ls[threadIdx.x + off];
            lq[threadIdx.x] += lq[threadIdx.x + off];
        }
        __syncthreads();
    }
    if (threadIdx.x < COUT) {
        atomicAdd(&sums[ch], ls[threadIdx.x]);
        atomicAdd(&sums[COUT + ch], lq[threadIdx.x]);
    }
}

// ---------------- pooling (batch is sorted) + FC ----------------
__global__ __launch_bounds__(256) void pool_kernel(const __half* __restrict__ t3,
                                                   const int* __restrict__ batch,
                                                   float* __restrict__ pooled) {
    __shared__ float tile[256][33];
    __shared__ int lb[256];
    int n = blockIdx.x * 256 + threadIdx.x;
    int valid = N_NODES - blockIdx.x * 256;
    if (valid > 256) valid = 256;
    if (n < N_NODES) {
        const uint4* r = (const uint4*)(t3 + (size_t)n * 32);
#pragma unroll
        for (int i = 0; i < 4; ++i) {
            uint4 v = r[i];
            float2 a = __half22float2(*(__half2*)&v.x);
            float2 b = __half22float2(*(__half2*)&v.y);
            float2 c = __half22float2(*(__half2*)&v.z);
            float2 d = __half22float2(*(__half2*)&v.w);
            tile[threadIdx.x][8 * i + 0] = a.x;
            tile[threadIdx.x][8 * i + 1] = a.y;
            tile[threadIdx.x][8 * i + 2] = b.x;
            tile[threadIdx.x][8 * i + 3] = b.y;
            tile[threadIdx.x][8 * i + 4] = c.x;
            tile[threadIdx.x][8 * i + 5] = c.y;
            tile[threadIdx.x][8 * i + 6] = d.x;
            tile[threadIdx.x][8 * i + 7] = d.y;
        }
        lb[threadIdx.x] = batch[n];
    }
    __syncthreads();
    if (threadIdx.x < 32) {
        int ch = threadIdx.x;
        float run = 0.f;
        int gp = lb[0];
        for (int r = 0; r < valid; ++r) {
            int g = lb[r];
            if (g != gp) {
                atomicAdd(&pooled[gp * 32 + ch], run);
                run = 0.f;
                gp = g;
            }
            run += tile[r][ch];
        }
        atomicAdd(&pooled[gp * 32 + ch], run);
    }
}

__global__ void final_kernel(const float* __restrict__ pooled, const int* __restrict__ cntg,
                             const float* __restrict__ bns, const float* __restrict__ g,
                             const float* __restrict__ bb, const float* __restrict__ fcw,
                             float* __restrict__ out) {
    __shared__ float sc3[32], sh3[32];
    if (threadIdx.x < 32) {
        int c = threadIdx.x;
        float mu = bns[c] * (1.f / N_NODES);
        float var = fmaxf(bns[32 + c] * (1.f / N_NODES) - mu * mu, 0.f);
        float s = g[c] * rsqrtf(var + EPS);
        sc3[c] = s;
        sh3[c] = bb[c] - mu * s;
    }
    __syncthreads();
    int i = threadIdx.x;
    if (i >= N_GRAPHS * 10) return;
    int gi = i / 10, o = i % 10;
    float rc = 1.f / fmaxf((float)cntg[gi], 1.f);
    float acc = 0.f;
#pragma unroll
    for (int d = 0; d < 32; ++d) {
        float pm = sc3[d] * (pooled[gi * 32 + d] * rc) + sh3[d];
        acc += pm * fcw[o * 32 + d];
    }
    out[i] = acc;
}

extern "C" void kernel_launch(void* const* d_in, const int* in_sizes, int n_in,
                              void* d_out, int out_size, void* d_ws, size_t ws_size,
                              hipStream_t stream) {
    const float* x   = (const float*)d_in[0];
    const int*   ei  = (const int*)d_in[1];
    const float* ea  = (const float*)d_in[2];
    const int*   bat = (const int*)d_in[3];
    const float* W1  = (const float*)d_in[4];
    const float* W2  = (const float*)d_in[5];
    const float* W3  = (const float*)d_in[6];
    const float* g1  = (const float*)d_in[7];
    const float* b1  = (const float*)d_in[8];
    const float* g2  = (const float*)d_in[9];
    const float* b2  = (const float*)d_in[10];
    const float* g3  = (const float*)d_in[11];
    const float* b3  = (const float*)d_in[12];
    const float* fcw = (const float*)d_in[13];
    float* out = (float*)d_out;
    char* ws = (char*)d_ws;

    int*    cntg   = (int*)(ws + OFF_CNTG);
    float*  bns1   = (float*)(ws + OFF_BNS1);
    float*  bns2   = (float*)(ws + OFF_BNS2);
    float*  bns3   = (float*)(ws + OFF_BNS3);
    float*  pooled = (float*)(ws + OFF_POOLED);
    int*    cbase  = (int*)(ws + OFF_CBASE);
    int*    btot   = (int*)(ws + OFF_BTOT);
    int*    rowptr = (int*)(ws + OFF_ROWPTR);
    int*    histM  = (int*)(ws + OFF_HISTM);
    uint2*  Es     = (uint2*)(ws + OFF_ES);
    uint2*  Ep     = (uint2*)(ws + OFF_EP);
    __half* t1     = (__half*)(ws + OFF_T1);
    __half* t2     = (__half*)(ws + OFF_T2);
    __half* t3     = (__half*)(ws + OFF_T3);

    const int* src = ei;
    const int* dst = ei + N_EDGES;

    hipMemsetAsync(ws, 0, ZERO_BYTES, stream);

    cnt_kernel<<<1, 64, 0, stream>>>(bat, cntg);
    k_hist<<<PBLK, 256, 0, stream>>>(dst, histM);
    k_scan1<<<NC, 256, 0, stream>>>(histM, btot);
    k_scan2<<<1, 256, 0, stream>>>(btot, cbase);
    k_part<<<PBLK, 256, 0, stream>>>(src, dst, (const float2*)ea, histM, cbase, Es);
    k_fine<<<NC, 256, 0, stream>>>(Es, cbase, rowptr, Ep);

    layer1_kernel<<<LBLK, 256, 0, stream>>>(x, rowptr, Ep, W1, t1);
    bnstats_kernel<8><<<256, 256, 0, stream>>>(t1, bns1);

    layer2_kernel<<<LBLK, 256, 0, stream>>>(t1, bns1, g1, b1, rowptr, Ep, W2, t2);
    bnstats_kernel<16><<<256, 256, 0, stream>>>(t2, bns2);

    layer3_kernel<<<LBLK, 256, 0, stream>>>(t2, bns2, g2, b2, rowptr, Ep, W3, t3);
    bnstats_kernel<32><<<256, 256, 0, stream>>>(t3, bns3);

    pool_kernel<<<NBLK, 256, 0, stream>>>(t3, bat, pooled);
    final_kernel<<<1, 640, 0, stream>>>(pooled, cntg, bns3, g3, b3, fcw, out);
}

// Round 9
// 224.124 us; speedup vs baseline: 1.2285x; 1.1345x over previous
//
#include <hip/hip_runtime.h>
#include <hip/hip_fp16.h>

#define N_NODES 100000
#define N_EDGES 3200000
#define N_GRAPHS 64
constexpr int NC    = 196;                 // coarse buckets of 512 nodes (196*512=100352)
constexpr int PBLK  = 256;                 // partition blocks
constexpr int CHUNK = N_EDGES / PBLK;      // 12500 edges/block (exact)
constexpr int NBLK  = (N_NODES + 255) / 256;
constexpr int LBLK  = N_NODES / 32;        // 3125 exact: 32 nodes/block, 8 lanes/node
constexpr int FCAP  = 18432;               // k_fine LDS record capacity (mean 16384 + 16 sigma)
#define EPS 1e-5f

// ---- workspace layout (bytes) ----
constexpr size_t OFF_CNTG   = 0x0;         // int[64]
constexpr size_t OFF_BNS1   = 0x400;       // float[16]
constexpr size_t OFF_BNS2   = 0x500;       // float[32]
constexpr size_t OFF_BNS3   = 0x700;       // float[64]
constexpr size_t OFF_POOLED = 0x1000;      // float[64*32] = 8KB
constexpr size_t ZERO_BYTES = 0x3000;      // memset [0, here)
constexpr size_t OFF_CBASE  = 0x4000;      // int[NC+1]
constexpr size_t OFF_BTOT   = 0x5000;      // int[NC]
constexpr size_t OFF_ROWPTR = 0x10000;     // int[N_NODES+1]
constexpr size_t OFF_HISTM  = 0x80000;     // int[NC*PBLK] ~200KB
constexpr size_t OFF_ES     = 0x200000;    // uint2[N_EDGES] 25.6MB (staging)
constexpr size_t OFF_EP     = 0x1B00000;   // uint2[N_EDGES] 25.6MB (CSR)
constexpr size_t OFF_T1     = 0x3400000;   // half[N_NODES*8]  1.6MB
constexpr size_t OFF_T2     = 0x3800000;   // half[N_NODES*16] 3.2MB
constexpr size_t OFF_T3     = 0x4000000;   // half[N_NODES*32] 6.4MB

// batch is sorted -> per-graph count via binary search (no atomics)
__global__ void cnt_kernel(const int* __restrict__ batch, int* __restrict__ cntg) {
    int g = threadIdx.x;
    if (g >= N_GRAPHS) return;
    int lo0 = 0, hi0 = N_NODES;
    while (lo0 < hi0) { int m = (lo0 + hi0) >> 1; if (batch[m] < g) lo0 = m + 1; else hi0 = m; }
    int lo1 = lo0, hi1 = N_NODES;
    while (lo1 < hi1) { int m = (lo1 + hi1) >> 1; if (batch[m] < g + 1) lo1 = m + 1; else hi1 = m; }
    cntg[g] = lo1 - lo0;
}

// per-block LDS coarse-bucket histogram (no global atomics)
__global__ __launch_bounds__(256) void k_hist(const int* __restrict__ dst,
                                              int* __restrict__ histM) {
    __shared__ int h[NC];
    for (int i = threadIdx.x; i < NC; i += 256) h[i] = 0;
    __syncthreads();
    int base = blockIdx.x * CHUNK;
    for (int i = threadIdx.x; i < CHUNK; i += 256)
        atomicAdd(&h[dst[base + i] >> 9], 1);
    __syncthreads();
    for (int i = threadIdx.x; i < NC; i += 256)
        histM[i * PBLK + blockIdx.x] = h[i];
}

// per-bucket exclusive scan over blocks; emit bucket totals
__global__ __launch_bounds__(256) void k_scan1(int* __restrict__ histM,
                                               int* __restrict__ btot) {
    __shared__ int sd[256];
    int b = blockIdx.x, t = threadIdx.x;
    int v = histM[b * PBLK + t];
    sd[t] = v;
    __syncthreads();
    for (int off = 1; off < 256; off <<= 1) {
        int x = (t >= off) ? sd[t - off] : 0;
        __syncthreads();
        sd[t] += x;
        __syncthreads();
    }
    histM[b * PBLK + t] = sd[t] - v;   // exclusive within bucket
    if (t == 255) btot[b] = sd[255];
}

// exclusive scan over bucket totals -> coarse bucket bases
__global__ __launch_bounds__(256) void k_scan2(const int* __restrict__ btot,
                                               int* __restrict__ cbase) {
    __shared__ int sd[256];
    int t = threadIdx.x;
    int v = (t < NC) ? btot[t] : 0;
    sd[t] = v;
    __syncthreads();
    for (int off = 1; off < 256; off <<= 1) {
        int x = (t >= off) ? sd[t - off] : 0;
        __syncthreads();
        sd[t] += x;
        __syncthreads();
    }
    if (t < NC) cbase[t] = sd[t] - v;
    if (t == 0) cbase[NC] = N_EDGES;
}

// partition edges into coarse-bucket sub-streams; record packed to 8B:
// w0 = src(17) | u0q[14:0]<<17 ; w1 = u0q[18:15] | u1q<<4 | dst_low9<<23   (u at 19 bits)
__global__ __launch_bounds__(256) void k_part(const int* __restrict__ src,
                                              const int* __restrict__ dst,
                                              const float2* __restrict__ ea,
                                              const int* __restrict__ histM,
                                              const int* __restrict__ cbase,
                                              uint2* __restrict__ Es) {
    __shared__ int cur[NC];
    for (int i = threadIdx.x; i < NC; i += 256)
        cur[i] = cbase[i] + histM[i * PBLK + blockIdx.x];
    __syncthreads();
    int base = blockIdx.x * CHUNK;
    for (int i = threadIdx.x; i < CHUNK; i += 256) {
        int e = base + i;
        int d = dst[e];
        float2 u = ea[e];
        float u0 = fminf(fmaxf(u.x, 0.f), 1.f);
        float u1 = fminf(fmaxf(u.y, 0.f), 1.f);
        unsigned u0q = __float2uint_rn(u0 * 524287.f);
        unsigned u1q = __float2uint_rn(u1 * 524287.f);
        unsigned w0 = (unsigned)src[e] | ((u0q & 0x7FFFu) << 17);
        unsigned w1 = (u0q >> 15) | (u1q << 4) | ((unsigned)(d & 511) << 23);
        int pos = atomicAdd(&cur[d >> 9], 1);
        Es[pos] = make_uint2(w0, w1);
    }
}

// per coarse bucket: LDS histogram -> scan -> rowptr -> LDS-staged scatter -> coalesced write
__global__ __launch_bounds__(1024) void k_fine(const uint2* __restrict__ Es,
                                               const int* __restrict__ cbase,
                                               int* __restrict__ rowptr,
                                               uint2* __restrict__ Ep) {
    extern __shared__ uint2 rec[];         // FCAP records (144KB dynamic)
    __shared__ int cnt[512];
    __shared__ int cur[512];
    __shared__ int sd[512];
    int b = blockIdx.x, t = threadIdx.x;
    int lo = cbase[b], hi = cbase[b + 1];
    int m = hi - lo;
    if (t < 512) cnt[t] = 0;
    __syncthreads();
    for (int i = lo + t; i < hi; i += 1024)
        atomicAdd(&cnt[Es[i].y >> 23], 1);
    __syncthreads();
    if (t < 512) sd[t] = cnt[t];
    __syncthreads();
    for (int off = 1; off < 512; off <<= 1) {
        int x = (t < 512 && t >= off) ? sd[t - off] : 0;
        __syncthreads();
        if (t < 512) sd[t] += x;
        __syncthreads();
    }
    if (t < 512) {
        int excl = sd[t] - cnt[t];
        cur[t] = excl;                     // bucket-relative
        int n = b * 512 + t;
        if (n < N_NODES) rowptr[n] = lo + excl;
    }
    if (b == NC - 1 && t == 0) rowptr[N_NODES] = N_EDGES;
    __syncthreads();
    if (m <= FCAP) {
        for (int i = lo + t; i < hi; i += 1024) {
            uint2 r = Es[i];
            int pos = atomicAdd(&cur[r.y >> 23], 1);
            rec[pos] = r;
        }
        __syncthreads();
        for (int i = t; i < m; i += 1024)   // coalesced stream-out
            Ep[lo + i] = rec[i];
    } else {
        // overflow fallback (statistically unreachable): direct global scatter
        for (int i = lo + t; i < hi; i += 1024) {
            uint2 r = Es[i];
            int pos = atomicAdd(&cur[r.y >> 23], 1);
            Ep[lo + pos] = r;
        }
    }
}

#define DECODE_EDGE(r)                                              \
    int s = r.x & 0x1FFFF;                                          \
    unsigned u0q = (r.x >> 17) | ((r.y & 0xFu) << 15);              \
    unsigned u1q = (r.y >> 4) & 0x7FFFFu;                           \
    float u0 = u0q * (1.f / 524287.f);                              \
    float u1 = u1q * (1.f / 524287.f);                              \
    float nu0 = 1.f - u0, nu1 = 1.f - u1;                           \
    float b0 = nu0 * nu1, b1 = u0 * nu1, b2 = nu0 * u1, b3 = u0 * u1;

// ---------------- layer 1: CIN=3, COUT=8, fp32 in, fp16 out; 8-way edge split ----------------
__global__ __launch_bounds__(256) void layer1_kernel(const float* __restrict__ xin,
                                                     const int* __restrict__ rowptr,
                                                     const uint2* __restrict__ Ep,
                                                     const float* __restrict__ W,
                                                     __half* __restrict__ tout) {
    __shared__ float Wl[96];               // [k][c][d] flat, same as global
    for (int i = threadIdx.x; i < 96; i += 256) Wl[i] = W[i];
    __syncthreads();
    int lane8 = threadIdx.x & 7;
    int n = blockIdx.x * 32 + (threadIdx.x >> 3);
    int e0 = rowptr[n], e1 = rowptr[n + 1];
    float z[12];
#pragma unroll
    for (int i = 0; i < 12; ++i) z[i] = 0.f;
#pragma unroll 2
    for (int j = e0 + lane8; j < e1; j += 8) {
        uint2 r = Ep[j];
        DECODE_EDGE(r)
        float x0 = xin[s * 3 + 0], x1 = xin[s * 3 + 1], x2 = xin[s * 3 + 2];
        z[0] += b0 * x0; z[1]  += b0 * x1; z[2]  += b0 * x2;
        z[3] += b1 * x0; z[4]  += b1 * x1; z[5]  += b1 * x2;
        z[6] += b2 * x0; z[7]  += b2 * x1; z[8]  += b2 * x2;
        z[9] += b3 * x0; z[10] += b3 * x1; z[11] += b3 * x2;
    }
#pragma unroll
    for (int i = 0; i < 12; ++i) {
        z[i] += __shfl_xor(z[i], 4);
        z[i] += __shfl_xor(z[i], 2);
        z[i] += __shfl_xor(z[i], 1);
    }
    float y = 0.f;
#pragma unroll
    for (int kc = 0; kc < 12; ++kc) y += z[kc] * Wl[kc * 8 + lane8];
    float invd = 1.f / fmaxf((float)(e1 - e0), 1.f);
    float v = y * invd;
    v = v > 0.f ? v : expm1f(v);
    tout[(size_t)n * 8 + lane8] = __float2half_rn(v);
}

// ------- layer 2: CIN=8, COUT=16; fp16 in/out; BN folded from sums (no bnfin) -------
__global__ __launch_bounds__(256) void layer2_kernel(const __half* __restrict__ xin,
                                                     const float* __restrict__ bns,
                                                     const float* __restrict__ g,
                                                     const float* __restrict__ bb,
                                                     const int* __restrict__ rowptr,
                                                     const uint2* __restrict__ Ep,
                                                     const float* __restrict__ W,
                                                     __half* __restrict__ tout) {
    __shared__ float scA[8], shA[8];
    __shared__ float4 Wl[140];             // f2 = k*35 + d4p*9 + c   (sc folded)
    __shared__ float shW[64];              // [k][16] = sum_c sh[c]*W[k][c][d]
    int t = threadIdx.x;
    if (t < 8) {
        float mu = bns[t] * (1.f / N_NODES);
        float var = fmaxf(bns[8 + t] * (1.f / N_NODES) - mu * mu, 0.f);
        float s = g[t] * rsqrtf(var + EPS);
        scA[t] = s;
        shA[t] = bb[t] - mu * s;
    }
    __syncthreads();
    if (t < 128) {
        int k = t >> 5, d4 = (t >> 3) & 3, c = t & 7;
        float4 w = ((const float4*)W)[(k * 8 + c) * 4 + d4];
        float s = scA[c];
        Wl[k * 35 + d4 * 9 + c] = make_float4(w.x * s, w.y * s, w.z * s, w.w * s);
    } else if (t < 192) {
        int j = t - 128;
        int k = j >> 4, d = j & 15;
        float acc = 0.f;
#pragma unroll
        for (int c = 0; c < 8; ++c) acc += shA[c] * W[(k * 8 + c) * 16 + d];
        shW[j] = acc;
    }
    __syncthreads();

    int lane8 = t & 7;
    int kq = lane8 & 3, h = lane8 >> 2;
    int ch = kq & 1;                       // c-half
    int eo = lane8 >> 1;                   // edge offset 0..3 (bits kq1,h)
    int n = blockIdx.x * 32 + (t >> 3);
    int e0 = rowptr[n], e1 = rowptr[n + 1];
    float z[16], S[4];
#pragma unroll
    for (int i = 0; i < 16; ++i) z[i] = 0.f;
#pragma unroll
    for (int i = 0; i < 4; ++i) S[i] = 0.f;
#pragma unroll 2
    for (int j = e0 + eo; j < e1; j += 4) {
        uint2 r = Ep[j];
        DECODE_EDGE(r)
        uint2 hv = *(const uint2*)(xin + (size_t)s * 8 + 4 * ch);
        float2 f0 = __half22float2(*(__half2*)&hv.x);
        float2 f1 = __half22float2(*(__half2*)&hv.y);
        S[0] += b0; S[1] += b1; S[2] += b2; S[3] += b3;
        z[0]  += b0 * f0.x; z[1]  += b0 * f0.y; z[2]  += b0 * f1.x; z[3]  += b0 * f1.y;
        z[4]  += b1 * f0.x; z[5]  += b1 * f0.y; z[6]  += b1 * f1.x; z[7]  += b1 * f1.y;
        z[8]  += b2 * f0.x; z[9]  += b2 * f0.y; z[10] += b2 * f1.x; z[11] += b2 * f1.y;
        z[12] += b3 * f0.x; z[13] += b3 * f0.y; z[14] += b3 * f1.x; z[15] += b3 * f1.y;
    }
    // edge-subset reduce (masks 4 then 2)
#pragma unroll
    for (int i = 0; i < 16; ++i) { z[i] += __shfl_xor(z[i], 4); z[i] += __shfl_xor(z[i], 2); }
#pragma unroll
    for (int i = 0; i < 4; ++i)  { S[i] += __shfl_xor(S[i], 4); S[i] += __shfl_xor(S[i], 2); }

    // y-partial: d-half by h, c-half by ch
    int laneW = 18 * h + 4 * ch;
    float y[8];
#pragma unroll
    for (int i = 0; i < 8; ++i) y[i] = 0.f;
#pragma unroll
    for (int k = 0; k < 4; ++k)
#pragma unroll
        for (int i = 0; i < 4; ++i) {
            float zc = z[k * 4 + i];
            int base = k * 35 + i + laneW;
#pragma unroll
            for (int d4 = 0; d4 < 2; ++d4) {
                float4 w = Wl[base + 9 * d4];
                y[4 * d4 + 0] += zc * w.x; y[4 * d4 + 1] += zc * w.y;
                y[4 * d4 + 2] += zc * w.z; y[4 * d4 + 3] += zc * w.w;
            }
        }
    // mask-1: sum c-halves, keep d-quarter by ch (static select)
    float y1[4];
#pragma unroll
    for (int i = 0; i < 4; ++i) {
        float a = y[i]     + __shfl_xor(y[i],     1);
        float b = y[4 + i] + __shfl_xor(y[4 + i], 1);
        y1[i] = ch ? b : a;
    }
    int qb = (kq >> 1) & 1;
    float f0 = qb ? y1[2] : y1[0];
    float f1 = qb ? y1[3] : y1[1];
    int d = h * 8 + ch * 4 + qb * 2;
    f0 += S[0] * shW[d]     + S[1] * shW[16 + d]     + S[2] * shW[32 + d]     + S[3] * shW[48 + d];
    f1 += S[0] * shW[d + 1] + S[1] * shW[16 + d + 1] + S[2] * shW[32 + d + 1] + S[3] * shW[48 + d + 1];
    float invd = 1.f / fmaxf((float)(e1 - e0), 1.f);
    f0 *= invd; f1 *= invd;
    f0 = f0 > 0.f ? f0 : expm1f(f0);
    f1 = f1 > 0.f ? f1 : expm1f(f1);
    *(__half2*)(tout + (size_t)n * 16 + d) = __floats2half2_rn(f0, f1);
}

// ------- layer 3: CIN=16, COUT=32; fp16 in/out; BN folded from sums (no bnfin) -------
__global__ __launch_bounds__(256) void layer3_kernel(const __half* __restrict__ xin,
                                                     const float* __restrict__ bns,
                                                     const float* __restrict__ g,
                                                     const float* __restrict__ bb,
                                                     const int* __restrict__ rowptr,
                                                     const uint2* __restrict__ Ep,
                                                     const float* __restrict__ W,
                                                     __half* __restrict__ tout) {
    __shared__ float scA[16], shA[16];
    __shared__ float4 Wl[580];             // f3 = k*145 + d4p*18 + (d4p>>2) + c + 2*(c>>3)
    __shared__ float shW[128];             // [k][32]
    int t = threadIdx.x;
    if (t < 16) {
        float mu = bns[t] * (1.f / N_NODES);
        float var = fmaxf(bns[16 + t] * (1.f / N_NODES) - mu * mu, 0.f);
        float s = g[t] * rsqrtf(var + EPS);
        scA[t] = s;
        shA[t] = bb[t] - mu * s;
    }
    __syncthreads();
    for (int i = t; i < 512; i += 256) {
        int k = i >> 7, d4 = (i >> 4) & 7, c = i & 15;
        float4 w = ((const float4*)W)[(k * 16 + c) * 8 + d4];
        float s = scA[c];
        Wl[k * 145 + d4 * 18 + (d4 >> 2) + c + 2 * (c >> 3)] =
            make_float4(w.x * s, w.y * s, w.z * s, w.w * s);
    }
    if (t < 128) {
        int k = t >> 5, d = t & 31;
        float acc = 0.f;
#pragma unroll
        for (int c = 0; c < 16; ++c) acc += shA[c] * W[(k * 16 + c) * 32 + d];
        shW[t] = acc;
    }
    __syncthreads();

    int lane8 = t & 7;
    int kq = lane8 & 3, h = lane8 >> 2;
    int n = blockIdx.x * 32 + (t >> 3);
    int e0 = rowptr[n], e1 = rowptr[n + 1];
    float z[16], S[4];
#pragma unroll
    for (int i = 0; i < 16; ++i) z[i] = 0.f;
#pragma unroll
    for (int i = 0; i < 4; ++i) S[i] = 0.f;
#pragma unroll 2
    for (int j = e0 + h; j < e1; j += 2) {
        uint2 r = Ep[j];
        DECODE_EDGE(r)
        uint2 hv = *(const uint2*)(xin + (size_t)s * 16 + 4 * kq);   // this lane's quarter
        float2 f0 = __half22float2(*(__half2*)&hv.x);
        float2 f1 = __half22float2(*(__half2*)&hv.y);
        S[0] += b0; S[1] += b1; S[2] += b2; S[3] += b3;
        z[0]  += b0 * f0.x; z[1]  += b0 * f0.y; z[2]  += b0 * f1.x; z[3]  += b0 * f1.y;
        z[4]  += b1 * f0.x; z[5]  += b1 * f0.y; z[6]  += b1 * f1.x; z[7]  += b1 * f1.y;
        z[8]  += b2 * f0.x; z[9]  += b2 * f0.y; z[10] += b2 * f1.x; z[11] += b2 * f1.y;
        z[12] += b3 * f0.x; z[13] += b3 * f0.y; z[14] += b3 * f1.x; z[15] += b3 * f1.y;
    }
    // h-reduce (edge halves)
#pragma unroll
    for (int i = 0; i < 16; ++i) z[i] += __shfl_xor(z[i], 4);
#pragma unroll
    for (int i = 0; i < 4; ++i)  S[i] += __shfl_xor(S[i], 4);

    // y-partial: d-half by h, c-quarter by kq  (bank-swizzled W reads)
    int laneW = 4 * kq + 2 * (kq >> 1) + 73 * h;
    float y[16];
#pragma unroll
    for (int i = 0; i < 16; ++i) y[i] = 0.f;
#pragma unroll
    for (int k = 0; k < 4; ++k)
#pragma unroll
        for (int i = 0; i < 4; ++i) {
            float zc = z[k * 4 + i];
            int base = k * 145 + i + laneW;
#pragma unroll
            for (int d4 = 0; d4 < 4; ++d4) {
                float4 w = Wl[base + 18 * d4];
                y[4 * d4 + 0] += zc * w.x; y[4 * d4 + 1] += zc * w.y;
                y[4 * d4 + 2] += zc * w.z; y[4 * d4 + 3] += zc * w.w;
            }
        }
    // select-tree reduce over c-quarters (masks 1 then 2), static indices
    float y1[8];
#pragma unroll
    for (int i = 0; i < 8; ++i) {
        float a = y[i]     + __shfl_xor(y[i],     1);
        float b = y[8 + i] + __shfl_xor(y[8 + i], 1);
        y1[i] = (kq & 1) ? b : a;
    }
    float y2[4];
#pragma unroll
    for (int i = 0; i < 4; ++i) {
        float a = y1[i]     + __shfl_xor(y1[i],     2);
        float b = y1[4 + i] + __shfl_xor(y1[4 + i], 2);
        y2[i] = (kq & 2) ? b : a;
    }
    int d = h * 16 + (kq & 1) * 8 + ((kq >> 1) & 1) * 4;
#pragma unroll
    for (int i = 0; i < 4; ++i)
        y2[i] += S[0] * shW[d + i] + S[1] * shW[32 + d + i] +
                 S[2] * shW[64 + d + i] + S[3] * shW[96 + d + i];
    float invd = 1.f / fmaxf((float)(e1 - e0), 1.f);
#pragma unroll
    for (int i = 0; i < 4; ++i) {
        float v = y2[i] * invd;
        y2[i] = v > 0.f ? v : expm1f(v);
    }
    __half2 h01 = __floats2half2_rn(y2[0], y2[1]);
    __half2 h23 = __floats2half2_rn(y2[2], y2[3]);
    uint2 st;
    st.x = *(unsigned*)&h01;
    st.y = *(unsigned*)&h23;
    *(uint2*)(tout + (size_t)n * 32 + d) = st;
}

// ---------------- BN stats (fp16 input, fp32 sums) ----------------
template <int COUT>
__global__ __launch_bounds__(256) void bnstats_kernel(const __half* __restrict__ t,
                                                      float* __restrict__ sums) {
    constexpr int ROWS = 256 / COUT;
    int ch = threadIdx.x % COUT;
    int r = threadIdx.x / COUT;
    float s = 0.f, q = 0.f;
    for (int n = blockIdx.x * ROWS + r; n < N_NODES; n += gridDim.x * ROWS) {
        float v = __half2float(t[(size_t)n * COUT + ch]);
        s += v;
        q += v * v;
    }
    __shared__ float ls[256], lq[256];
    ls[threadIdx.x] = s; lq[threadIdx.x] = q;
    __syncthreads();
    for (int off = 128; off >= COUT; off >>= 1) {
        if (threadIdx.x < off) {
            ls[threadIdx.x] += ls[threadIdx.x + off];
            lq[threadIdx.x] += lq[threadIdx.x + off];
        }
        __syncthreads();
    }
    if (threadIdx.x < COUT) {
        atomicAdd(&sums[ch], ls[threadIdx.x]);
        atomicAdd(&sums[COUT + ch], lq[threadIdx.x]);
    }
}

// ---------------- pooling (batch is sorted) + FC ----------------
__global__ __launch_bounds__(256) void pool_kernel(const __half* __restrict__ t3,
                                                   const int* __restrict__ batch,
                                                   float* __restrict__ pooled) {
    __shared__ float tile[256][33];
    __shared__ int lb[256];
    int n = blockIdx.x * 256 + threadIdx.x;
    int valid = N_NODES - blockIdx.x * 256;
    if (valid > 256) valid = 256;
    if (n < N_NODES) {
        const uint4* r = (const uint4*)(t3 + (size_t)n * 32);
#pragma unroll
        for (int i = 0; i < 4; ++i) {
            uint4 v = r[i];
            float2 a = __half22float2(*(__half2*)&v.x);
            float2 b = __half22float2(*(__half2*)&v.y);
            float2 c = __half22float2(*(__half2*)&v.z);
            float2 d = __half22float2(*(__half2*)&v.w);
            tile[threadIdx.x][8 * i + 0] = a.x;
            tile[threadIdx.x][8 * i + 1] = a.y;
            tile[threadIdx.x][8 * i + 2] = b.x;
            tile[threadIdx.x][8 * i + 3] = b.y;
            tile[threadIdx.x][8 * i + 4] = c.x;
            tile[threadIdx.x][8 * i + 5] = c.y;
            tile[threadIdx.x][8 * i + 6] = d.x;
            tile[threadIdx.x][8 * i + 7] = d.y;
        }
        lb[threadIdx.x] = batch[n];
    }
    __syncthreads();
    if (threadIdx.x < 32) {
        int ch = threadIdx.x;
        float run = 0.f;
        int gp = lb[0];
        for (int r = 0; r < valid; ++r) {
            int g = lb[r];
            if (g != gp) {
                atomicAdd(&pooled[gp * 32 + ch], run);
                run = 0.f;
                gp = g;
            }
            run += tile[r][ch];
        }
        atomicAdd(&pooled[gp * 32 + ch], run);
    }
}

__global__ void final_kernel(const float* __restrict__ pooled, const int* __restrict__ cntg,
                             const float* __restrict__ bns, const float* __restrict__ g,
                             const float* __restrict__ bb, const float* __restrict__ fcw,
                             float* __restrict__ out) {
    __shared__ float sc3[32], sh3[32];
    if (threadIdx.x < 32) {
        int c = threadIdx.x;
        float mu = bns[c] * (1.f / N_NODES);
        float var = fmaxf(bns[32 + c] * (1.f / N_NODES) - mu * mu, 0.f);
        float s = g[c] * rsqrtf(var + EPS);
        sc3[c] = s;
        sh3[c] = bb[c] - mu * s;
    }
    __syncthreads();
    int i = threadIdx.x;
    if (i >= N_GRAPHS * 10) return;
    int gi = i / 10, o = i % 10;
    float rc = 1.f / fmaxf((float)cntg[gi], 1.f);
    float acc = 0.f;
#pragma unroll
    for (int d = 0; d < 32; ++d) {
        float pm = sc3[d] * (pooled[gi * 32 + d] * rc) + sh3[d];
        acc += pm * fcw[o * 32 + d];
    }
    out[i] = acc;
}

extern "C" void kernel_launch(void* const* d_in, const int* in_sizes, int n_in,
                              void* d_out, int out_size, void* d_ws, size_t ws_size,
                              hipStream_t stream) {
    const float* x   = (const float*)d_in[0];
    const int*   ei  = (const int*)d_in[1];
    const float* ea  = (const float*)d_in[2];
    const int*   bat = (const int*)d_in[3];
    const float* W1  = (const float*)d_in[4];
    const float* W2  = (const float*)d_in[5];
    const float* W3  = (const float*)d_in[6];
    const float* g1  = (const float*)d_in[7];
    const float* b1  = (const float*)d_in[8];
    const float* g2  = (const float*)d_in[9];
    const float* b2  = (const float*)d_in[10];
    const float* g3  = (const float*)d_in[11];
    const float* b3  = (const float*)d_in[12];
    const float* fcw = (const float*)d_in[13];
    float* out = (float*)d_out;
    char* ws = (char*)d_ws;

    int*    cntg   = (int*)(ws + OFF_CNTG);
    float*  bns1   = (float*)(ws + OFF_BNS1);
    float*  bns2   = (float*)(ws + OFF_BNS2);
    float*  bns3   = (float*)(ws + OFF_BNS3);
    float*  pooled = (float*)(ws + OFF_POOLED);
    int*    cbase  = (int*)(ws + OFF_CBASE);
    int*    btot   = (int*)(ws + OFF_BTOT);
    int*    rowptr = (int*)(ws + OFF_ROWPTR);
    int*    histM  = (int*)(ws + OFF_HISTM);
    uint2*  Es     = (uint2*)(ws + OFF_ES);
    uint2*  Ep     = (uint2*)(ws + OFF_EP);
    __half* t1     = (__half*)(ws + OFF_T1);
    __half* t2     = (__half*)(ws + OFF_T2);
    __half* t3     = (__half*)(ws + OFF_T3);

    const int* src = ei;
    const int* dst = ei + N_EDGES;

    // allow >64KB dynamic LDS for k_fine (host-side, idempotent, capture-safe)
    hipFuncSetAttribute((const void*)k_fine,
                        hipFuncAttributeMaxDynamicSharedMemorySize, FCAP * 8);

    hipMemsetAsync(ws, 0, ZERO_BYTES, stream);

    cnt_kernel<<<1, 64, 0, stream>>>(bat, cntg);
    k_hist<<<PBLK, 256, 0, stream>>>(dst, histM);
    k_scan1<<<NC, 256, 0, stream>>>(histM, btot);
    k_scan2<<<1, 256, 0, stream>>>(btot, cbase);
    k_part<<<PBLK, 256, 0, stream>>>(src, dst, (const float2*)ea, histM, cbase, Es);
    k_fine<<<NC, 1024, FCAP * 8, stream>>>(Es, cbase, rowptr, Ep);

    layer1_kernel<<<LBLK, 256, 0, stream>>>(x, rowptr, Ep, W1, t1);
    bnstats_kernel<8><<<256, 256, 0, stream>>>(t1, bns1);

    layer2_kernel<<<LBLK, 256, 0, stream>>>(t1, bns1, g1, b1, rowptr, Ep, W2, t2);
    bnstats_kernel<16><<<256, 256, 0, stream>>>(t2, bns2);

    layer3_kernel<<<LBLK, 256, 0, stream>>>(t2, bns2, g2, b2, rowptr, Ep, W3, t3);
    bnstats_kernel<32><<<256, 256, 0, stream>>>(t3, bns3);

    pool_kernel<<<NBLK, 256, 0, stream>>>(t3, bat, pooled);
    final_kernel<<<1, 640, 0, stream>>>(pooled, cntg, bns3, g3, b3, fcw, out);
}